// Round 1
// baseline (104.640 us; speedup 1.0000x reference)
//
#include <hip/hip_runtime.h>

// ---------------------------------------------------------------------------
// Stacked 3-layer LSTM step + projection, B=256, I=512, H=1024, V=512 (fp32 io)
// Strategy: bf16 MFMA (16x16x32) GEMMs with fp32 accumulate.
//   pack:   x,h0,h1,h2 fp32 -> bf16 (once)
//   gemm_z: z = A1@W1 + A2@W2 + b   (A bf16 in ws, W fp32 streamed->bf16)
//   gates:  i,f,g,o -> h_new, c_new (fp32) + h_new bf16 for next layer
// ---------------------------------------------------------------------------

typedef __attribute__((ext_vector_type(8))) short short8_t;            // 8 bf16 (MFMA frag)
typedef __attribute__((ext_vector_type(8))) unsigned short ushort8_t;  // 16B ld/st
typedef __attribute__((ext_vector_type(4))) unsigned short ushort4_t;  // 8B st
typedef __attribute__((ext_vector_type(4))) float f32x4;               // MFMA acc / 16B ld

__device__ __forceinline__ unsigned short f2bf(float f) {
    union { float f; unsigned u; } v; v.f = f;
    unsigned r = v.u + 0x7FFFu + ((v.u >> 16) & 1u);   // RTNE (finite inputs)
    return (unsigned short)(r >> 16);
}

// ---------------------------------------------------------------------------
// GEMM: Z[256][N] = A1[256][K1] @ W1[K1][N] + A2[256][K2] @ W2[K2][N] + bias
// A* are bf16 (ushort bits), W* are fp32 (converted to bf16 in-register).
// Block: 512 threads (8 waves), owns all 256 rows x 16 cols. Grid = N/16.
// Each wave computes two 16x16 output tiles, K-loop in steps of 64.
// 2-phase reg-prefetch pipeline: global loads for tile t+1 fly during MFMA of t.
// ---------------------------------------------------------------------------
#define GN 16
#define KT 64

__global__ __launch_bounds__(512, 2)
void gemm_z(const unsigned short* __restrict__ A1, const float* __restrict__ W1, int K1,
            const unsigned short* __restrict__ A2, const float* __restrict__ W2, int K2,
            const float* __restrict__ bias, float* __restrict__ Z, int N)
{
    __shared__ unsigned short Al[256 * KT];  // 32 KB, 16B-chunk XOR swizzled
    __shared__ unsigned short Wl[GN * KT];   // 2 KB, [n][k] (transposed), swizzled

    const int tid  = threadIdx.x;
    const int lane = tid & 63;
    const int w    = tid >> 6;      // wave 0..7
    const int lg   = lane >> 4;     // 0..3
    const int lr   = lane & 15;
    const int n0   = blockIdx.x * GN;
    const int m0   = w * 32;

    ushort8_t pa[4];   // prefetched A chunks (4 x 16B per thread)
    f32x4     pw;      // prefetched W row-chunk (4 fp32)

    const int nt1 = K1 >> 6;
    const int nt2 = K2 >> 6;
    const int ntt = nt1 + nt2;

    f32x4 acc0 = {0.f, 0.f, 0.f, 0.f};
    f32x4 acc1 = {0.f, 0.f, 0.f, 0.f};

    auto load_tile_regs = [&](const unsigned short* A, int ldA, const float* W, int ldW, int k0) {
#pragma unroll
        for (int it = 0; it < 4; ++it) {
            int c = tid + it * 512;         // 2048 chunks = 256 rows x 8
            int row = c >> 3, cc = c & 7;
            pa[it] = *(const ushort8_t*)(A + (size_t)row * ldA + k0 + cc * 8);
        }
        if (tid < 256) {
            int kr = tid >> 2, cq = tid & 3;    // 64 rows x 4 float4
            pw = *(const f32x4*)(W + (size_t)(k0 + kr) * ldW + n0 + cq * 4);
        }
    };

    auto store_tile_lds = [&]() {
#pragma unroll
        for (int it = 0; it < 4; ++it) {
            int c = tid + it * 512;
            int row = c >> 3, cc = c & 7;
            int sl = cc ^ (row & 7);        // 16B-chunk swizzle
            *(ushort8_t*)(Al + row * KT + sl * 8) = pa[it];
        }
        if (tid < 256) {
            int kr = tid >> 2, cq = tid & 3;
            unsigned short bs[4] = { f2bf(pw[0]), f2bf(pw[1]), f2bf(pw[2]), f2bf(pw[3]) };
            int chunk = kr >> 3, within = kr & 7;
#pragma unroll
            for (int j = 0; j < 4; ++j) {
                int n = cq * 4 + j;         // transposed write: W_lds[n][k]
                Wl[n * KT + ((chunk ^ (n & 7)) << 3) + within] = bs[j];
            }
        }
    };

    auto compute_tile = [&]() {
#pragma unroll
        for (int ks = 0; ks < 2; ++ks) {    // two K=32 MFMA steps per KT=64
            int chunk = ks * 4 + lg;
            short8_t bf = *(const short8_t*)(Wl + lr * KT + ((chunk ^ (lr & 7)) << 3));
            {
                int row = m0 + lr;
                short8_t af = *(const short8_t*)(Al + row * KT + ((chunk ^ (row & 7)) << 3));
                acc0 = __builtin_amdgcn_mfma_f32_16x16x32_bf16(af, bf, acc0, 0, 0, 0);
            }
            {
                int row = m0 + 16 + lr;
                short8_t af = *(const short8_t*)(Al + row * KT + ((chunk ^ (row & 7)) << 3));
                acc1 = __builtin_amdgcn_mfma_f32_16x16x32_bf16(af, bf, acc1, 0, 0, 0);
            }
        }
    };

    // prologue: prefetch tile 0
    load_tile_regs(A1, K1, W1, N, 0);

    for (int t = 0; t < ntt; ++t) {
        __syncthreads();                    // prior compute done before LDS overwrite
        store_tile_lds();
        __syncthreads();
        int tn = t + 1;
        if (tn < ntt) {                     // issue next tile's global loads now
            if (tn < nt1) load_tile_regs(A1, K1, W1, N, tn * KT);
            else          load_tile_regs(A2, K2, W2, N, (tn - nt1) * KT);
        }
        compute_tile();                     // MFMA while next loads are in flight
    }

    // epilogue: D mapping col=lane&15, row=4*(lane>>4)+reg  [verified m89/m91]
    float bn = bias[n0 + lr];
#pragma unroll
    for (int r = 0; r < 4; ++r) {
        int m = m0 + lg * 4 + r;
        Z[(size_t)m * N + n0 + lr]        = acc0[r] + bn;
        Z[(size_t)(m + 16) * N + n0 + lr] = acc1[r] + bn;
    }
}

// ---------------------------------------------------------------------------
// Gates: z[256][4096] -> h_new, c_new (fp32) + h_new bf16
// ---------------------------------------------------------------------------
__global__ __launch_bounds__(256)
void lstm_gates(const float* __restrict__ Z, const float* __restrict__ c_old,
                float* __restrict__ h_out, float* __restrict__ c_out,
                unsigned short* __restrict__ h_bf)
{
    int t = blockIdx.x * 256 + threadIdx.x;   // 65536 threads, 4 elems each
    int b = t >> 8;
    int n = (t & 255) << 2;
    const float* zrow = Z + (size_t)b * 4096;
    f32x4 iv = *(const f32x4*)(zrow + n);
    f32x4 fv = *(const f32x4*)(zrow + 1024 + n);
    f32x4 gv = *(const f32x4*)(zrow + 2048 + n);
    f32x4 ov = *(const f32x4*)(zrow + 3072 + n);
    f32x4 cv = *(const f32x4*)(c_old + (size_t)b * 1024 + n);

    f32x4 hn, cn;
    ushort4_t hb;
#pragma unroll
    for (int j = 0; j < 4; ++j) {
        float ii = 1.f / (1.f + __expf(-iv[j]));
        float ff = 1.f / (1.f + __expf(-fv[j]));
        float gg = tanhf(gv[j]);
        float oo = 1.f / (1.f + __expf(-ov[j]));
        float c2 = ff * cv[j] + ii * gg;
        cn[j] = c2;
        float h2 = oo * tanhf(c2);
        hn[j] = h2;
        hb[j] = f2bf(h2);
    }
    *(f32x4*)(c_out + (size_t)b * 1024 + n) = cn;
    *(f32x4*)(h_out + (size_t)b * 1024 + n) = hn;
    *(ushort4_t*)(h_bf + (size_t)b * 1024 + n) = hb;
}

// ---------------------------------------------------------------------------
// Pack fp32 -> bf16 for x, h0, h1, h2 (229376 float4s total)
// ---------------------------------------------------------------------------
__global__ __launch_bounds__(256)
void pack_bf16(const float* __restrict__ x,  const float* __restrict__ h0,
               const float* __restrict__ h1, const float* __restrict__ h2,
               unsigned short* __restrict__ xb,  unsigned short* __restrict__ h0b,
               unsigned short* __restrict__ h1b, unsigned short* __restrict__ h2b)
{
    int t = blockIdx.x * 256 + threadIdx.x;
    const float* src; unsigned short* dst; int off;
    if (t < 32768)       { src = x;  dst = xb;  off = t; }
    else if (t < 98304)  { src = h0; dst = h0b; off = t - 32768; }
    else if (t < 163840) { src = h1; dst = h1b; off = t - 98304; }
    else                 { src = h2; dst = h2b; off = t - 163840; }
    f32x4 v = *(const f32x4*)(src + (size_t)off * 4);
    ushort4_t o;
#pragma unroll
    for (int j = 0; j < 4; ++j) o[j] = f2bf(v[j]);
    *(ushort4_t*)(dst + (size_t)off * 4) = o;
}

// ---------------------------------------------------------------------------
extern "C" void kernel_launch(void* const* d_in, const int* in_sizes, int n_in,
                              void* d_out, int out_size, void* d_ws, size_t ws_size,
                              hipStream_t stream)
{
    const float* x  = (const float*)d_in[0];
    const float* h0 = (const float*)d_in[1];
    const float* c0 = (const float*)d_in[2];
    const float* h1 = (const float*)d_in[3];
    const float* c1 = (const float*)d_in[4];
    const float* h2 = (const float*)d_in[5];
    const float* c2 = (const float*)d_in[6];
    const float* W0 = (const float*)d_in[7];
    const float* U0 = (const float*)d_in[8];
    const float* b0 = (const float*)d_in[9];
    const float* W1 = (const float*)d_in[10];
    const float* U1 = (const float*)d_in[11];
    const float* b1 = (const float*)d_in[12];
    const float* W2 = (const float*)d_in[13];
    const float* U2 = (const float*)d_in[14];
    const float* b2 = (const float*)d_in[15];
    const float* Wp = (const float*)d_in[16];
    const float* bp = (const float*)d_in[17];

    float* out    = (float*)d_out;
    float* logits = out;                    // [256,512]
    float* h0n = out + 131072;              // [256,1024] each below
    float* c0n = h0n + 262144;
    float* h1n = c0n + 262144;
    float* c1n = h1n + 262144;
    float* h2n = c1n + 262144;
    float* c2n = h2n + 262144;

    char* ws = (char*)d_ws;
    float*          zbuf = (float*)ws;                        // 4 MB
    unsigned short* xb   = (unsigned short*)(ws + 4194304);   // 256x512 bf16
    unsigned short* h0b  = (unsigned short*)(ws + 4456448);   // 256x1024 bf16 each
    unsigned short* h1b  = (unsigned short*)(ws + 4980736);
    unsigned short* h2b  = (unsigned short*)(ws + 5505024);
    unsigned short* h0nb = (unsigned short*)(ws + 6029312);
    unsigned short* h1nb = (unsigned short*)(ws + 6553600);
    unsigned short* h2nb = (unsigned short*)(ws + 7077888);

    pack_bf16<<<896, 256, 0, stream>>>(x, h0, h1, h2, xb, h0b, h1b, h2b);

    // layer 0: z = x@W0 + h0@U0 + b0
    gemm_z<<<256, 512, 0, stream>>>(xb, W0, 512, h0b, U0, 1024, b0, zbuf, 4096);
    lstm_gates<<<256, 256, 0, stream>>>(zbuf, c0, h0n, c0n, h0nb);

    // layer 1: z = h0n@W1 + h1@U1 + b1
    gemm_z<<<256, 512, 0, stream>>>(h0nb, W1, 1024, h1b, U1, 1024, b1, zbuf, 4096);
    lstm_gates<<<256, 256, 0, stream>>>(zbuf, c1, h1n, c1n, h1nb);

    // layer 2: z = h1n@W2 + h2@U2 + b2
    gemm_z<<<256, 512, 0, stream>>>(h1nb, W2, 1024, h2b, U2, 1024, b2, zbuf, 4096);
    lstm_gates<<<256, 256, 0, stream>>>(zbuf, c2, h2n, c2n, h2nb);

    // projection: logits = h2n@Wp + bp
    gemm_z<<<32, 512, 0, stream>>>(h2nb, Wp, 1024, (const unsigned short*)nullptr,
                                   (const float*)nullptr, 0, bp, logits, 512);
}

// Round 2
// 75.786 us; speedup vs baseline: 1.3807x; 1.3807x over previous
//
#include <hip/hip_runtime.h>

// ---------------------------------------------------------------------------
// Stacked 3-layer LSTM step + projection, B=256, I=512, H=1024, V=512 (fp32 io)
// bf16 MFMA GEMMs, BN=32 column strips, K-split-2 partials, LDS double-buffer,
// 1 barrier/tile, 2-tile-unrolled ping-pong register prefetch.
// ---------------------------------------------------------------------------

typedef __attribute__((ext_vector_type(8))) short short8_t;            // 8 bf16 (MFMA frag)
typedef __attribute__((ext_vector_type(8))) unsigned short ushort8_t;  // 16B ld/st
typedef __attribute__((ext_vector_type(4))) unsigned short ushort4_t;  // 8B st
typedef __attribute__((ext_vector_type(4))) float f32x4;               // MFMA acc / 16B ld

__device__ __forceinline__ unsigned short f2bf(float f) {
    union { float f; unsigned u; } v; v.f = f;
    unsigned r = v.u + 0x7FFFu + ((v.u >> 16) & 1u);   // RTNE (finite inputs)
    return (unsigned short)(r >> 16);
}

#define KT 64

// ---------------------------------------------------------------------------
// Z_partial[kb][256][N] = A[256][kb-th K-slice] @ W[kb-th K-slice][N]
// A = concat(A1[256][K1], A2[256][Ktot-K1]) bf16; W = concat(W1,W2) fp32 rows.
// Block: 512 thr (8 waves), BM=256 (full), BN=32, K-slice = Ktot/nsplit.
// grid = (N/32) * nsplit;  kb = bid & (nsplit-1), ns = bid >> (nsplit-1).
// Wave w: rows [w*32, w*32+32), all 32 cols -> 2x2 MFMA tiles.
// ---------------------------------------------------------------------------
__global__ __launch_bounds__(512, 2)
void gemm32(const unsigned short* __restrict__ A1, const float* __restrict__ W1, int K1,
            const unsigned short* __restrict__ A2, const float* __restrict__ W2,
            int N, int Ktot, int nsplit, float* __restrict__ zp)
{
    __shared__ unsigned short Al0[256 * KT];   // 32 KB  (16B-chunk XOR swizzled)
    __shared__ unsigned short Al1[256 * KT];   // 32 KB
    __shared__ unsigned short Wl0[32 * KT];    // 4 KB   ([n][k] transposed, swizzled)
    __shared__ unsigned short Wl1[32 * KT];    // 4 KB

    const int tid  = threadIdx.x;
    const int lane = tid & 63;
    const int w    = tid >> 6;
    const int lg   = lane >> 4;
    const int lr   = lane & 15;
    const int bid  = blockIdx.x;
    const int kb   = bid & (nsplit - 1);
    const int ns   = bid >> (nsplit - 1);
    const int n0   = ns * 32;
    const int m0   = w * 32;
    const int klen = Ktot >> (nsplit - 1);
    const int kbeg = kb * klen;
    const int nt   = klen >> 6;            // tiles (even for all our shapes)

    const int wkr = tid >> 3;              // W row within tile 0..63
    const int wcq = tid & 7;               // W float4-col 0..7

    ushort8_t paA[4], paB[4];              // ping-pong A prefetch (static idx)
    f32x4     pwA,   pwB;                  // ping-pong W prefetch

    f32x4 acc00 = {0,0,0,0}, acc01 = {0,0,0,0}, acc10 = {0,0,0,0}, acc11 = {0,0,0,0};

    auto issue = [&](int t, ushort8_t (&pa)[4], f32x4& pw) {
        int k0 = kbeg + t * KT;
        const unsigned short* A; const float* Wm; int ldA, krel;
        if (k0 < K1) { A = A1; Wm = W1; ldA = K1;        krel = k0; }
        else         { A = A2; Wm = W2; ldA = Ktot - K1; krel = k0 - K1; }
#pragma unroll
        for (int it = 0; it < 4; ++it) {
            int c = tid + it * 512;        // 2048 chunks = 256 rows x 8
            int row = c >> 3, cc = c & 7;
            pa[it] = *(const ushort8_t*)(A + (size_t)row * ldA + krel + cc * 8);
        }
        pw = *(const f32x4*)(Wm + (size_t)(krel + wkr) * N + n0 + wcq * 4);
    };

    auto stage = [&](ushort8_t (&pa)[4], f32x4& pw,
                     unsigned short* al, unsigned short* wl) {
#pragma unroll
        for (int it = 0; it < 4; ++it) {
            int c = tid + it * 512;
            int row = c >> 3, cc = c & 7;
            *(ushort8_t*)(al + row * KT + ((cc ^ (row & 7)) << 3)) = pa[it];
        }
        unsigned short bs[4] = { f2bf(pw[0]), f2bf(pw[1]), f2bf(pw[2]), f2bf(pw[3]) };
        int kch = wkr >> 3, kwi = wkr & 7;
#pragma unroll
        for (int j = 0; j < 4; ++j) {
            int n = wcq * 4 + j;           // transposed: Wl[n][k]
            wl[n * KT + ((kch ^ (n & 7)) << 3) + kwi] = bs[j];
        }
    };

    auto compute = [&](const unsigned short* al, const unsigned short* wl) {
#pragma unroll
        for (int ks = 0; ks < 2; ++ks) {
            int ch = ks * 4 + lg;
            int nb0 = lr, nb1 = 16 + lr;
            short8_t b0f = *(const short8_t*)(wl + nb0 * KT + ((ch ^ (nb0 & 7)) << 3));
            short8_t b1f = *(const short8_t*)(wl + nb1 * KT + ((ch ^ (nb1 & 7)) << 3));
            int r0 = m0 + lr, r1 = m0 + 16 + lr;
            short8_t a0f = *(const short8_t*)(al + r0 * KT + ((ch ^ (r0 & 7)) << 3));
            short8_t a1f = *(const short8_t*)(al + r1 * KT + ((ch ^ (r1 & 7)) << 3));
            acc00 = __builtin_amdgcn_mfma_f32_16x16x32_bf16(a0f, b0f, acc00, 0, 0, 0);
            acc01 = __builtin_amdgcn_mfma_f32_16x16x32_bf16(a0f, b1f, acc01, 0, 0, 0);
            acc10 = __builtin_amdgcn_mfma_f32_16x16x32_bf16(a1f, b0f, acc10, 0, 0, 0);
            acc11 = __builtin_amdgcn_mfma_f32_16x16x32_bf16(a1f, b1f, acc11, 0, 0, 0);
        }
    };

    // prologue
    issue(0, paA, pwA);
    stage(paA, pwA, Al0, Wl0);
    issue(1, paB, pwB);
    __syncthreads();                       // publish buf0

    for (int t = 0; t < nt; t += 2) {
        if (t + 2 < nt) issue(t + 2, paA, pwA);
        stage(paB, pwB, Al1, Wl1);         // tile t+1 -> buf1
        compute(Al0, Wl0);                 // tile t
        __syncthreads();                   // publish buf1
        if (t + 3 < nt) issue(t + 3, paB, pwB);
        if (t + 2 < nt) stage(paA, pwA, Al0, Wl0);
        compute(Al1, Wl1);                 // tile t+1
        __syncthreads();                   // publish buf0
    }

    // epilogue: D mapping col=lane&15, row=4*(lane>>4)+reg  [m89/m91]
    float* zrow = zp + (size_t)kb * 256 * N;
#pragma unroll
    for (int r = 0; r < 4; ++r) {
        int ma = m0 + lg * 4 + r;
        int mb = ma + 16;
        zrow[(size_t)ma * N + n0 + lr]      = acc00[r];
        zrow[(size_t)ma * N + n0 + 16 + lr] = acc01[r];
        zrow[(size_t)mb * N + n0 + lr]      = acc10[r];
        zrow[(size_t)mb * N + n0 + 16 + lr] = acc11[r];
    }
}

// ---------------------------------------------------------------------------
// Gates: z = zp0 + zp1 + bias -> h_new, c_new (fp32) + h_new bf16
// ---------------------------------------------------------------------------
__global__ __launch_bounds__(256)
void lstm_gates(const float* __restrict__ zp0, const float* __restrict__ zp1,
                const float* __restrict__ bias, const float* __restrict__ c_old,
                float* __restrict__ h_out, float* __restrict__ c_out,
                unsigned short* __restrict__ h_bf)
{
    int t = blockIdx.x * 256 + threadIdx.x;   // 65536 threads, 4 elems each
    int b = t >> 8;
    int n = (t & 255) << 2;
    const float* z0 = zp0 + (size_t)b * 4096;
    f32x4 iv = *(const f32x4*)(z0 + n);
    f32x4 fv = *(const f32x4*)(z0 + 1024 + n);
    f32x4 gv = *(const f32x4*)(z0 + 2048 + n);
    f32x4 ov = *(const f32x4*)(z0 + 3072 + n);
    if (zp1) {
        const float* z1 = zp1 + (size_t)b * 4096;
        iv += *(const f32x4*)(z1 + n);
        fv += *(const f32x4*)(z1 + 1024 + n);
        gv += *(const f32x4*)(z1 + 2048 + n);
        ov += *(const f32x4*)(z1 + 3072 + n);
    }
    iv += *(const f32x4*)(bias + n);
    fv += *(const f32x4*)(bias + 1024 + n);
    gv += *(const f32x4*)(bias + 2048 + n);
    ov += *(const f32x4*)(bias + 3072 + n);
    f32x4 cv = *(const f32x4*)(c_old + (size_t)b * 1024 + n);

    f32x4 hn, cn;
    ushort4_t hb;
#pragma unroll
    for (int j = 0; j < 4; ++j) {
        float ii = 1.f / (1.f + __expf(-iv[j]));
        float ff = 1.f / (1.f + __expf(-fv[j]));
        float gg = tanhf(gv[j]);
        float oo = 1.f / (1.f + __expf(-ov[j]));
        float c2 = ff * cv[j] + ii * gg;
        cn[j] = c2;
        float h2 = oo * tanhf(c2);
        hn[j] = h2;
        hb[j] = f2bf(h2);
    }
    *(f32x4*)(c_out + (size_t)b * 1024 + n) = cn;
    *(f32x4*)(h_out + (size_t)b * 1024 + n) = hn;
    *(ushort4_t*)(h_bf + (size_t)b * 1024 + n) = hb;
}

// ---------------------------------------------------------------------------
// logits = zp0 + zp1 + bp   (proj partial reduce), N=512
// ---------------------------------------------------------------------------
__global__ __launch_bounds__(256)
void finalize_proj(const float* __restrict__ zp0, const float* __restrict__ zp1,
                   const float* __restrict__ bp, float* __restrict__ logits)
{
    int t = blockIdx.x * 256 + threadIdx.x;   // 32768 threads x 4 elems
    int i = t * 4;
    f32x4 v = *(const f32x4*)(zp0 + i);
    if (zp1) v += *(const f32x4*)(zp1 + i);
    v += *(const f32x4*)(bp + (i & 511));
    *(f32x4*)(logits + i) = v;
}

// ---------------------------------------------------------------------------
// Pack fp32 -> bf16 for x, h0, h1, h2
// ---------------------------------------------------------------------------
__global__ __launch_bounds__(256)
void pack_bf16(const float* __restrict__ x,  const float* __restrict__ h0,
               const float* __restrict__ h1, const float* __restrict__ h2,
               unsigned short* __restrict__ xb,  unsigned short* __restrict__ h0b,
               unsigned short* __restrict__ h1b, unsigned short* __restrict__ h2b)
{
    int t = blockIdx.x * 256 + threadIdx.x;
    const float* src; unsigned short* dst; int off;
    if (t < 32768)       { src = x;  dst = xb;  off = t; }
    else if (t < 98304)  { src = h0; dst = h0b; off = t - 32768; }
    else if (t < 163840) { src = h1; dst = h1b; off = t - 98304; }
    else                 { src = h2; dst = h2b; off = t - 163840; }
    f32x4 v = *(const f32x4*)(src + (size_t)off * 4);
    ushort4_t o;
#pragma unroll
    for (int j = 0; j < 4; ++j) o[j] = f2bf(v[j]);
    *(ushort4_t*)(dst + (size_t)off * 4) = o;
}

// ---------------------------------------------------------------------------
extern "C" void kernel_launch(void* const* d_in, const int* in_sizes, int n_in,
                              void* d_out, int out_size, void* d_ws, size_t ws_size,
                              hipStream_t stream)
{
    const float* x  = (const float*)d_in[0];
    const float* h0 = (const float*)d_in[1];
    const float* c0 = (const float*)d_in[2];
    const float* h1 = (const float*)d_in[3];
    const float* c1 = (const float*)d_in[4];
    const float* h2 = (const float*)d_in[5];
    const float* c2 = (const float*)d_in[6];
    const float* W0 = (const float*)d_in[7];
    const float* U0 = (const float*)d_in[8];
    const float* b0 = (const float*)d_in[9];
    const float* W1 = (const float*)d_in[10];
    const float* U1 = (const float*)d_in[11];
    const float* b1 = (const float*)d_in[12];
    const float* W2 = (const float*)d_in[13];
    const float* U2 = (const float*)d_in[14];
    const float* b2 = (const float*)d_in[15];
    const float* Wp = (const float*)d_in[16];
    const float* bp = (const float*)d_in[17];

    float* out    = (float*)d_out;
    float* logits = out;                    // [256,512]
    float* h0n = out + 131072;              // [256,1024] each below
    float* c0n = h0n + 262144;
    float* h1n = c0n + 262144;
    float* c1n = h1n + 262144;
    float* h2n = c1n + 262144;
    float* c2n = h2n + 262144;

    // K-split-2 needs: zp 8MB + xb 256KB + 6x h-bf16 512KB = 11,796,480 B
    const size_t need2 = 8388608ull + 262144ull + 6ull * 524288ull;
    const int nsplit = (ws_size >= need2) ? 2 : 1;
    const size_t zbytes = (size_t)nsplit * 4194304ull;

    char* ws = (char*)d_ws;
    float*          zp   = (float*)ws;                         // [nsplit][256][4096]
    unsigned short* xb   = (unsigned short*)(ws + zbytes);
    unsigned short* h0b  = (unsigned short*)(ws + zbytes + 262144);
    unsigned short* h1b  = (unsigned short*)(ws + zbytes + 262144 + 524288);
    unsigned short* h2b  = (unsigned short*)(ws + zbytes + 262144 + 2*524288);
    unsigned short* h0nb = (unsigned short*)(ws + zbytes + 262144 + 3*524288);
    unsigned short* h1nb = (unsigned short*)(ws + zbytes + 262144 + 4*524288);
    unsigned short* h2nb = (unsigned short*)(ws + zbytes + 262144 + 5*524288);

    const float* zp1  = (nsplit == 2) ? zp + 1048576 : nullptr;  // layer partial 1
    const float* zpp1 = (nsplit == 2) ? zp + 131072  : nullptr;  // proj partial 1

    pack_bf16<<<896, 256, 0, stream>>>(x, h0, h1, h2, xb, h0b, h1b, h2b);

    // layer 0: z = x@W0 + h0@U0   (K1=512, Ktot=1536)
    gemm32<<<128 * nsplit, 512, 0, stream>>>(xb, W0, 512, h0b, U0, 4096, 1536, nsplit, zp);
    lstm_gates<<<256, 256, 0, stream>>>(zp, zp1, b0, c0, h0n, c0n, h0nb);

    // layer 1: z = h0n@W1 + h1@U1  (K1=1024, Ktot=2048)
    gemm32<<<128 * nsplit, 512, 0, stream>>>(h0nb, W1, 1024, h1b, U1, 4096, 2048, nsplit, zp);
    lstm_gates<<<256, 256, 0, stream>>>(zp, zp1, b1, c1, h1n, c1n, h1nb);

    // layer 2: z = h1n@W2 + h2@U2  (K1=1024, Ktot=2048)
    gemm32<<<128 * nsplit, 512, 0, stream>>>(h1nb, W2, 1024, h2b, U2, 4096, 2048, nsplit, zp);
    lstm_gates<<<256, 256, 0, stream>>>(zp, zp1, b2, c2, h2n, c2n, h2nb);

    // projection: logits = h2n@Wp + bp  (K=1024, N=512; reuses zp region)
    gemm32<<<16 * nsplit, 512, 0, stream>>>(h2nb, Wp, 1024,
                                            (const unsigned short*)nullptr,
                                            (const float*)nullptr, 512, 1024, nsplit, zp);
    finalize_proj<<<128, 256, 0, stream>>>(zp, zpp1, bp, logits);
}